// Round 8
// baseline (477.865 us; speedup 1.0000x reference)
//
#include <hip/hip_runtime.h>

#define DD 128

typedef _Float16 f16x8 __attribute__((ext_vector_type(8)));
typedef unsigned short u16x8 __attribute__((ext_vector_type(8)));
typedef unsigned short u16x4 __attribute__((ext_vector_type(4)));
typedef float f32x4 __attribute__((ext_vector_type(4)));

__device__ __forceinline__ float sigmoidf_(float v){ return 1.f/(1.f+__expf(-v)); }
__device__ __forceinline__ float tanhf_(float v){
  float e2 = __expf(2.f*v);
  return 1.f - 2.f/(e2 + 1.f);
}
__device__ __forceinline__ float h2f(unsigned short u){
  _Float16 h; __builtin_memcpy(&h, &u, 2); return (float)h;
}
__device__ __forceinline__ unsigned short f2h(float v){
  _Float16 h = (_Float16)v; unsigned short u; __builtin_memcpy(&u, &h, 2); return u;
}

// drain remaining edges [i,e) for one node, accumulating 8 features at octet q
__device__ __forceinline__ void gather_drain(const unsigned short* __restrict__ phc,
        const int2* __restrict__ csr, int i, int e, int q, float* acc){
  for (; i + 8 <= e; i += 8){
    int2 ed[8]; u16x8 R[8];
    #pragma unroll
    for (int u = 0; u < 8; u++) ed[u] = csr[i+u];
    #pragma unroll
    for (int u = 0; u < 8; u++) R[u] = *(const u16x8*)(phc + (size_t)ed[u].x*DD + q*8);
    #pragma unroll
    for (int u = 0; u < 8; u++){
      union { int i; float f; } c; c.i = ed[u].y;
      #pragma unroll
      for (int t = 0; t < 8; t++)
        acc[t] = fmaf(c.f, h2f((unsigned short)R[u][t]), acc[t]);
    }
  }
  if (i + 4 <= e){
    int2 ed[4]; u16x8 R[4];
    #pragma unroll
    for (int u = 0; u < 4; u++) ed[u] = csr[i+u];
    #pragma unroll
    for (int u = 0; u < 4; u++) R[u] = *(const u16x8*)(phc + (size_t)ed[u].x*DD + q*8);
    #pragma unroll
    for (int u = 0; u < 4; u++){
      union { int i; float f; } c; c.i = ed[u].y;
      #pragma unroll
      for (int t = 0; t < 8; t++)
        acc[t] = fmaf(c.f, h2f((unsigned short)R[u][t]), acc[t]);
    }
    i += 4;
  }
  for (; i < e; i++){
    int2 ed = csr[i];
    union { int i; float f; } c; c.i = ed.y;
    u16x8 R = *(const u16x8*)(phc + (size_t)ed.x*DD + q*8);
    #pragma unroll
    for (int t = 0; t < 8; t++)
      acc[t] = fmaf(c.f, h2f((unsigned short)R[t]), acc[t]);
  }
}

// ---------- fused pre-pass 1: weight prep  ∪  encoder matvec+stats  ∪  dst histogram ----------
#define PREP_B 416   // (2*384*128 + 64*128)/256
__global__ void __launch_bounds__(256) k_pre1(
        const float* __restrict__ W_ih, const float* __restrict__ W_hh,
        const float* __restrict__ W_dec, const float* __restrict__ x,
        const float* __restrict__ W_enc, const int* __restrict__ dst,
        unsigned short* __restrict__ Wih_h, unsigned short* __restrict__ Whh_h,
        unsigned short* __restrict__ Wd_h, unsigned short* __restrict__ h0,
        float* __restrict__ stats, int* __restrict__ counts, int N, int E){
  const int tid = threadIdx.x;
  const int gb = blockIdx.x;
  const int TOT = 384*128;
  if (gb < PREP_B){
    int idx = gb*256 + tid;
    if (idx < 2*TOT){
      const float* W = (idx < TOT) ? W_ih : W_hh;
      unsigned short* D = (idx < TOT) ? Wih_h : Whh_h;
      int fi = (idx < TOT) ? idx : idx - TOT;
      int t = fi & 7;
      int l = (fi >> 3) & 63;
      int ks = (fi >> 9) & 3;
      int nt = fi >> 11;
      int fg = nt / 3, gate = nt % 3;
      int j = gate*128 + fg*16 + (l & 15);
      int k = ks*32 + ((l >> 4) & 3)*8 + t;
      D[fi] = f2h(W[j*128 + k]);
    } else if (idx < 2*TOT + 64*128){
      int fi2 = idx - 2*TOT;
      int t  = fi2 & 7;
      int l  = (fi2 >> 3) & 63;
      int ks = (fi2 >> 9) & 3;
      int jt = fi2 >> 11;
      int j = jt*16 + (l & 15);
      int k = ks*32 + ((l >> 4) & 3)*8 + t;
      Wd_h[fi2] = f2h(W_dec[j*128 + k]);
    }
  } else if (gb < PREP_B + 256){
    const int b = gb - PREP_B;
    const int f = tid & 127;
    const int sub = tid >> 7;
    const float w0 = W_enc[f*3], w1 = W_enc[f*3+1], w2 = W_enc[f*3+2];
    const int chunk = (N + 255) / 256;
    const int n0 = b * chunk;
    const int n1 = (n0 + chunk < N) ? (n0 + chunk) : N;
    float s = 0.f, q = 0.f;
    for (int n = n0 + sub; n < n1; n += 2){
      float x0 = x[n*3], x1 = x[n*3+1], x2 = x[n*3+2];
      float h = x0*w0 + x1*w1 + x2*w2;
      unsigned short hu = f2h(h);
      float hq = h2f(hu);
      h0[(size_t)n*DD + f] = hu;
      s += hq; q += hq*hq;
    }
    atomicAdd(&stats[f], s);
    atomicAdd(&stats[DD+f], q);
  } else {
    int e = (gb - PREP_B - 256)*256 + tid;
    if (e < E) atomicAdd(&counts[dst[e]], 1);
  }
}

// ---------- scan chain ----------
__global__ void __launch_bounds__(256) k_scan_part(const int* __restrict__ counts,
                                                   int* __restrict__ partials, int N){
  int i = blockIdx.x*256 + threadIdx.x;
  int v = (i < N) ? counts[i] : 0;
  #pragma unroll
  for (int off = 32; off > 0; off >>= 1) v += __shfl_down(v, off, 64);
  __shared__ int red[4];
  if ((threadIdx.x & 63) == 0) red[threadIdx.x >> 6] = v;
  __syncthreads();
  if (threadIdx.x == 0) partials[blockIdx.x] = red[0]+red[1]+red[2]+red[3];
}

__global__ void __launch_bounds__(256) k_scan_mid(int* __restrict__ partials, int P,
                                                  int* __restrict__ offsets, int N){
  __shared__ int lds[4];
  __shared__ int carry_s;
  const int lane = threadIdx.x & 63, wid = threadIdx.x >> 6;
  if (threadIdx.x == 0) carry_s = 0;
  __syncthreads();
  for (int base = 0; base < P; base += 256){
    int i = base + threadIdx.x;
    int v = (i < P) ? partials[i] : 0;
    int orig = v;
    #pragma unroll
    for (int off = 1; off < 64; off <<= 1){
      int u = __shfl_up(v, off, 64);
      if (lane >= off) v += u;
    }
    if (lane == 63) lds[wid] = v;
    __syncthreads();
    if (threadIdx.x == 0){
      int s = carry_s;
      for (int k = 0; k < 4; k++){ int t = lds[k]; lds[k] = s; s += t; }
      carry_s = s;
    }
    __syncthreads();
    int excl = v - orig + lds[wid];
    if (i < P) partials[i] = excl;
    __syncthreads();
  }
  if (threadIdx.x == 0) offsets[N] = carry_s;
}

__global__ void __launch_bounds__(256) k_scan_expand(const int* __restrict__ counts,
        const int* __restrict__ partials, int* __restrict__ offsets,
        int* __restrict__ cursors, int N){
  int i = blockIdx.x*256 + threadIdx.x;
  int v = (i < N) ? counts[i] : 0;
  int orig = v;
  const int lane = threadIdx.x & 63, wid = threadIdx.x >> 6;
  #pragma unroll
  for (int off = 1; off < 64; off <<= 1){
    int u = __shfl_up(v, off, 64);
    if (lane >= off) v += u;
  }
  __shared__ int lds[4];
  if (lane == 63) lds[wid] = v;
  __syncthreads();
  int wbase = 0;
  for (int k = 0; k < wid; k++) wbase += lds[k];
  int excl = partials[blockIdx.x] + wbase + v - orig;
  if (i < N){ offsets[i] = excl; cursors[i] = excl; }
}

// ---------- fused pre-pass 2: vectorized BN+ReLU apply  ∪  CSR fill ----------
__global__ void __launch_bounds__(256) k_pre2(
        const unsigned short* __restrict__ h0, const float* __restrict__ gamma,
        const float* __restrict__ beta, const float* __restrict__ stats,
        unsigned short* __restrict__ ph,
        const int* __restrict__ src, const int* __restrict__ dst,
        const float* __restrict__ norm, int* __restrict__ cursors,
        int2* __restrict__ csr, int N, int E, int AB8){
  const int tid = threadIdx.x;
  if ((int)blockIdx.x < AB8){
    int idx8 = (blockIdx.x*256 + tid) * 8;
    if (idx8 >= N*DD) return;
    int f0 = idx8 & (DD-1);
    u16x8 hv = *(const u16x8*)(h0 + idx8);
    float4 ga = *(const float4*)(gamma + f0);
    float4 gb = *(const float4*)(gamma + f0 + 4);
    float4 ba = *(const float4*)(beta + f0);
    float4 bb = *(const float4*)(beta + f0 + 4);
    float4 sa = *(const float4*)(stats + f0);
    float4 sb = *(const float4*)(stats + f0 + 4);
    float4 qa = *(const float4*)(stats + DD + f0);
    float4 qb = *(const float4*)(stats + DD + f0 + 4);
    float g[8] = {ga.x,ga.y,ga.z,ga.w,gb.x,gb.y,gb.z,gb.w};
    float b[8] = {ba.x,ba.y,ba.z,ba.w,bb.x,bb.y,bb.z,bb.w};
    float s[8] = {sa.x,sa.y,sa.z,sa.w,sb.x,sb.y,sb.z,sb.w};
    float q[8] = {qa.x,qa.y,qa.z,qa.w,qb.x,qb.y,qb.z,qb.w};
    const float invN = 1.f / (float)N;
    u16x8 outv;
    #pragma unroll
    for (int t = 0; t < 8; t++){
      float mu = s[t] * invN;
      float var = q[t] * invN - mu*mu;
      float v = (h2f(hv[t]) - mu) * rsqrtf(var + 1e-5f) * g[t] + b[t];
      outv[t] = f2h(fmaxf(v, 0.f));
    }
    *(u16x8*)(ph + idx8) = outv;
  } else {
    int e = ((int)blockIdx.x - AB8)*256 + tid;
    if (e >= E) return;
    int p = atomicAdd(&cursors[dst[e]], 1);
    union { float f; int i; } c; c.f = norm[e];
    csr[p] = make_int2(src[e], c.i);
  }
}

// ---------- fused layer (0..3): 256 thr / 32 nodes, 6+6-deep paired gather -> LDS -> MFMA ----------
__global__ void __launch_bounds__(256, 4) k_layer(
        const unsigned short* __restrict__ phc,
        unsigned short* __restrict__ phn,
        unsigned short* __restrict__ agg_out,
        const int* __restrict__ offsets, const int2* __restrict__ csr,
        const unsigned short* __restrict__ Wih_h, const unsigned short* __restrict__ Whh_h,
        const float* __restrict__ b_ih, const float* __restrict__ b_hh, int N){
  __shared__ unsigned short s_a[32*DD];
  const int tid = threadIdx.x;
  const int n0 = blockIdx.x * 32;

  // ---- phase 1: paired gather — group (tid>>4) owns nodes m and m+16, 12 rows in flight ----
  {
    const int m = tid >> 4;      // 0..15
    const int q = tid & 15;      // feature octet
    const int nA = n0 + m;
    const int nB = n0 + 16 + m;
    float aA[8], aB[8];
    #pragma unroll
    for (int t = 0; t < 8; t++){ aA[t] = 0.f; aB[t] = 0.f; }
    int iA = 0, eA = 0, iB = 0, eB = 0;
    if (nA < N){ iA = offsets[nA]; eA = offsets[nA+1]; }
    if (nB < N){ iB = offsets[nB]; eB = offsets[nB+1]; }

    // joint hot loop: 6 edges of A + 6 edges of B in flight together
    while (iA + 6 <= eA && iB + 6 <= eB){
      int2 edA[6], edB[6];
      #pragma unroll
      for (int u = 0; u < 6; u++){ edA[u] = csr[iA+u]; edB[u] = csr[iB+u]; }
      u16x8 RA[6], RB[6];
      #pragma unroll
      for (int u = 0; u < 6; u++){
        RA[u] = *(const u16x8*)(phc + (size_t)edA[u].x*DD + q*8);
        RB[u] = *(const u16x8*)(phc + (size_t)edB[u].x*DD + q*8);
      }
      #pragma unroll
      for (int u = 0; u < 6; u++){
        union { int i; float f; } cA, cB; cA.i = edA[u].y; cB.i = edB[u].y;
        #pragma unroll
        for (int t = 0; t < 8; t++){
          aA[t] = fmaf(cA.f, h2f((unsigned short)RA[u][t]), aA[t]);
          aB[t] = fmaf(cB.f, h2f((unsigned short)RB[u][t]), aB[t]);
        }
      }
      iA += 6; iB += 6;
    }
    gather_drain(phc, csr, iA, eA, q, aA);
    gather_drain(phc, csr, iB, eB, q, aB);

    u16x8 vA, vB;
    #pragma unroll
    for (int t = 0; t < 8; t++){ vA[t] = f2h(aA[t]); vB[t] = f2h(aB[t]); }
    if (nA < N) *(u16x8*)(agg_out + (size_t)nA*DD + q*8) = vA;
    if (nB < N) *(u16x8*)(agg_out + (size_t)nB*DD + q*8) = vB;
    const int ccA = q ^ (m & 7);
    *(u16x8*)(s_a + m*DD + ccA*8) = vA;
    *(u16x8*)(s_a + (16+m)*DD + ccA*8) = vB;   // (16+m)&7 == m&7
  }
  __syncthreads();   // the only barrier: LDS A-frags ready

  // ---- phase 2+3 per feature group (wave w -> fg w*2+g), 2 node-tiles ----
  const int w = tid >> 6, l = tid & 63, ar = l & 15, aq = l >> 4;
  int r0 = n0 + ar;      if (r0 >= N) r0 = N-1;
  int r1 = n0 + 16 + ar; if (r1 >= N) r1 = N-1;
  const size_t p0 = (size_t)r0*DD + aq*8;
  const size_t p1 = (size_t)r1*DD + aq*8;
  const int sw = ar & 7;

  for (int g = 0; g < 2; g++){
    const int fg = w*2 + g;
    f32x4 acc_i[2][3], acc_h[2][3];
    #pragma unroll
    for (int ta = 0; ta < 2; ta++)
      #pragma unroll
      for (int t = 0; t < 3; t++){
        acc_i[ta][t] = (f32x4){0.f,0.f,0.f,0.f};
        acc_h[ta][t] = (f32x4){0.f,0.f,0.f,0.f};
      }

    #pragma unroll
    for (int ks = 0; ks < 4; ks++){
      const int c = (ks*4 + aq) ^ sw;
      f16x8 ih0 = *(const f16x8*)(s_a + ar*DD       + c*8);
      f16x8 ih1 = *(const f16x8*)(s_a + (16+ar)*DD  + c*8);
      f16x8 hh0 = *(const f16x8*)(phc + p0 + ks*32);
      f16x8 hh1 = *(const f16x8*)(phc + p1 + ks*32);
      #pragma unroll
      for (int t = 0; t < 3; t++){
        size_t bo = ((size_t)((fg*3 + t)*4 + ks)*64 + l)*8;
        f16x8 bih = *(const f16x8*)(Wih_h + bo);
        f16x8 bhh = *(const f16x8*)(Whh_h + bo);
        acc_i[0][t] = __builtin_amdgcn_mfma_f32_16x16x32_f16(ih0, bih, acc_i[0][t], 0, 0, 0);
        acc_i[1][t] = __builtin_amdgcn_mfma_f32_16x16x32_f16(ih1, bih, acc_i[1][t], 0, 0, 0);
        acc_h[0][t] = __builtin_amdgcn_mfma_f32_16x16x32_f16(hh0, bhh, acc_h[0][t], 0, 0, 0);
        acc_h[1][t] = __builtin_amdgcn_mfma_f32_16x16x32_f16(hh1, bhh, acc_h[1][t], 0, 0, 0);
      }
    }

    const int f = fg*16 + ar;
    const float bir = b_ih[f], biz = b_ih[128+f], bin_ = b_ih[256+f];
    const float bhr = b_hh[f], bhz = b_hh[128+f], bhn = b_hh[256+f];
    #pragma unroll
    for (int ta = 0; ta < 2; ta++){
      #pragma unroll
      for (int r = 0; r < 4; r++){
        int n = n0 + ta*16 + aq*4 + r;
        if (n < N){
          float sir = acc_i[ta][0][r] + bir, shr = acc_h[ta][0][r] + bhr;
          float siz = acc_i[ta][1][r] + biz, shz = acc_h[ta][1][r] + bhz;
          float sin_ = acc_i[ta][2][r] + bin_, shn = acc_h[ta][2][r] + bhn;
          float rr = sigmoidf_(sir + shr);
          float zz = sigmoidf_(siz + shz);
          float nn = tanhf_(sin_ + rr*shn);
          size_t o = (size_t)n*DD + f;
          float hp = h2f(phc[o]);
          float h = (1.f - zz)*nn + zz*hp;
          phn[o] = f2h(h);
        }
      }
    }
  }
}

// ---------- decoder stage 1: 16 nodes/block, gather + layer-sum -> fp16 LDS -> MFMA matvec ----------
__global__ void __launch_bounds__(256, 8) k_dec1(const unsigned short* __restrict__ hbn,
        const unsigned short* __restrict__ aggs, size_t NF,
        const unsigned short* __restrict__ ph5,
        const int* __restrict__ offsets, const int2* __restrict__ csr,
        const unsigned short* __restrict__ Wd_h, unsigned short* __restrict__ y1,
        float* __restrict__ stats_d, int N){
  __shared__ unsigned short zs[16*DD];
  __shared__ unsigned short stage[16*64];
  const int tid = threadIdx.x;
  const int n0 = blockIdx.x * 16;

  // ---- phase A: gather + layer-sum ----
  {
    const int m = tid >> 4;      // node slot 0..15
    const int q = tid & 15;      // feature octet
    const int n = n0 + m;
    float acc[8];
    #pragma unroll
    for (int t = 0; t < 8; t++) acc[t] = 0.f;
    if (n < N){
      size_t o = (size_t)n*DD + q*8;
      u16x8 hb = *(const u16x8*)(hbn + o);
      #pragma unroll
      for (int t = 0; t < 8; t++) acc[t] = h2f(hb[t]);
      #pragma unroll
      for (int l = 0; l < 4; l++){
        u16x8 ag = *(const u16x8*)(aggs + l*NF + o);
        #pragma unroll
        for (int t = 0; t < 8; t++) acc[t] += h2f(ag[t]);
      }
      gather_drain(ph5, csr, offsets[n], offsets[n+1], q, acc);
    }
    u16x8 vh;
    #pragma unroll
    for (int t = 0; t < 8; t++) vh[t] = f2h(acc[t] * (1.f/6.f));
    const int cc = q ^ (m & 7);
    *(u16x8*)(zs + m*DD + cc*8) = vh;
  }
  __syncthreads();

  // ---- phase B: MFMA matvec z(16x128) x Wd^T(128x64), wave w -> j-tile w ----
  const int w = tid >> 6, l = tid & 63, ar = l & 15, aq = l >> 4;
  const int sw = ar & 7;
  f32x4 acc = (f32x4){0.f,0.f,0.f,0.f};
  #pragma unroll
  for (int ks = 0; ks < 4; ks++){
    const int c = (ks*4 + aq) ^ sw;
    f16x8 a = *(const f16x8*)(zs + ar*DD + c*8);
    f16x8 b = *(const f16x8*)(Wd_h + ((size_t)(w*4 + ks)*64 + l)*8);
    acc = __builtin_amdgcn_mfma_f32_16x16x32_f16(a, b, acc, 0, 0, 0);
  }
  float s = 0.f, q2 = 0.f;
  #pragma unroll
  for (int r = 0; r < 4; r++){
    int n = n0 + aq*4 + r;
    float v = acc[r];
    if (n < N){
      stage[(aq*4 + r)*64 + w*16 + ar] = f2h(v);
      s += v; q2 += v*v;
    }
  }
  s  += __shfl_xor(s, 16, 64);  s  += __shfl_xor(s, 32, 64);
  q2 += __shfl_xor(q2, 16, 64); q2 += __shfl_xor(q2, 32, 64);
  if (aq == 0){
    float* st = stats_d + (size_t)(blockIdx.x & 7)*128;
    atomicAdd(&st[w*16 + ar], s);
    atomicAdd(&st[64 + w*16 + ar], q2);
  }
  __syncthreads();
  // ---- coalesced fp16 y1 write: 256 threads x 4 u16 = 16*64 ----
  {
    int idx = tid * 4;
    int n = n0 + (idx >> 6);
    if (n < N)
      *(u16x4*)(y1 + (size_t)n0*64 + idx) = *(const u16x4*)(stage + idx);
  }
}

// ---------- decoder stage 2: sum stats copies, bn + relu + dot ----------
__global__ void __launch_bounds__(256) k_dec2(const unsigned short* __restrict__ y1,
        const float* __restrict__ gamma, const float* __restrict__ beta,
        const float* __restrict__ W_dec2, const float* __restrict__ stats_d,
        float* __restrict__ out, int N){
  const int j = threadIdx.x & 63;
  const int g = threadIdx.x >> 6;
  const int n = blockIdx.x*4 + g;
  if (n >= N) return;
  float ssum = 0.f, qsum = 0.f;
  #pragma unroll
  for (int c = 0; c < 8; c++){
    ssum += stats_d[c*128 + j];
    qsum += stats_d[c*128 + 64 + j];
  }
  float invN = 1.f / (float)N;
  float mu = ssum * invN;
  float var = qsum * invN - mu*mu;
  float v = (h2f(y1[(size_t)n*64 + j]) - mu) * rsqrtf(var + 1e-5f) * gamma[j] + beta[j];
  v = fmaxf(v, 0.f) * W_dec2[j];
  for (int off = 32; off > 0; off >>= 1) v += __shfl_down(v, off, 64);
  if (j == 0) out[n] = v;
}

extern "C" void kernel_launch(void* const* d_in, const int* in_sizes, int n_in,
                              void* d_out, int out_size, void* d_ws, size_t ws_size,
                              hipStream_t stream) {
  const int N = in_sizes[0] / 3;
  const int E = in_sizes[1] / 2;
  const int P = (N + 255) / 256;
  const int HIST_B = (E + 255) / 256;
  const int AB8 = (N*DD/8 + 255) / 256;

  const float* x     = (const float*)d_in[0];
  const int*   ei    = (const int*)d_in[1];
  const int*   src   = ei;
  const int*   dst   = ei + E;
  const float* norm  = (const float*)d_in[2];
  const float* W_enc = (const float*)d_in[3];
  const float* g_e   = (const float*)d_in[4];
  const float* b_e   = (const float*)d_in[5];
  const float* W_ih  = (const float*)d_in[6];
  const float* W_hh  = (const float*)d_in[7];
  const float* b_ih  = (const float*)d_in[8];
  const float* b_hh  = (const float*)d_in[9];
  const float* W_dec = (const float*)d_in[10];
  const float* g_d   = (const float*)d_in[11];
  const float* b_d   = (const float*)d_in[12];
  const float* W_dec2= (const float*)d_in[13];
  float* out = (float*)d_out;

  float* ws = (float*)d_ws;
  const size_t NF = (size_t)N * DD;
  float* scr    = ws;                        // NF fp32 region: h0 (fp16, pre) / y1 (fp16, decode)
  unsigned short* h0h = (unsigned short*)scr;
  unsigned short* y1h = (unsigned short*)scr; // h0 dead after k_pre2
  float* stats  = scr + NF;                  // 256 enc + 1024 dec
  float* Wt_dec = stats + 1280;              // region: 64*128 floats (Wd_h uses first 16KB)
  unsigned short* Wd_h  = (unsigned short*)Wt_dec;
  unsigned short* Wih_h = (unsigned short*)(Wt_dec + 64*128);
  unsigned short* Whh_h = Wih_h + 384*128;
  unsigned short* ph_A  = Whh_h + 384*128;   // NF ushorts each; ph_A = post-BN h (pristine, = hbn)
  unsigned short* ph_B  = ph_A + NF;
  unsigned short* ph_C  = ph_B + NF;
  unsigned short* aggs  = ph_C + NF;         // 4 * NF ushorts (layers 0..3)
  int*   counts  = (int*)(aggs + 4*NF);      // N
  int*   offsets = counts + N;               // N+1
  int*   cursors = offsets + N + 1;          // N
  int*   partials= cursors + N;              // P
  int2*  csr     = (int2*)(partials + P);    // E int2 (src, norm-bits)

  hipMemsetAsync(stats, 0, 1280*sizeof(float), stream);
  hipMemsetAsync(counts, 0, (size_t)N*sizeof(int), stream);

  k_pre1<<<PREP_B + 256 + HIST_B, 256, 0, stream>>>(
      W_ih, W_hh, W_dec, x, W_enc, dst,
      Wih_h, Whh_h, Wd_h, h0h, stats, counts, N, E);
  k_scan_part<<<P, 256, 0, stream>>>(counts, partials, N);
  k_scan_mid<<<1, 256, 0, stream>>>(partials, P, offsets, N);
  k_scan_expand<<<P, 256, 0, stream>>>(counts, partials, offsets, cursors, N);
  k_pre2<<<AB8 + HIST_B, 256, 0, stream>>>(
      h0h, g_e, b_e, stats, ph_A,
      src, dst, norm, cursors, csr, N, E, AB8);

  // layers ping-pong through B/C, leaving ph_A (post-BN h) pristine for the decoder
  const int UB = (N + 31) / 32;
  k_layer<<<UB, 256, 0, stream>>>(ph_A, ph_B, aggs + (size_t)0*NF, offsets, csr,
                                  Wih_h, Whh_h, b_ih, b_hh, N);
  k_layer<<<UB, 256, 0, stream>>>(ph_B, ph_C, aggs + (size_t)1*NF, offsets, csr,
                                  Wih_h, Whh_h, b_ih, b_hh, N);
  k_layer<<<UB, 256, 0, stream>>>(ph_C, ph_B, aggs + (size_t)2*NF, offsets, csr,
                                  Wih_h, Whh_h, b_ih, b_hh, N);
  k_layer<<<UB, 256, 0, stream>>>(ph_B, ph_C, aggs + (size_t)3*NF, offsets, csr,
                                  Wih_h, Whh_h, b_ih, b_hh, N);

  k_dec1<<<(N + 15)/16, 256, 0, stream>>>(ph_A, aggs, NF, ph_C, offsets, csr,
                                          Wd_h, y1h, stats + 256, N);
  k_dec2<<<(N + 3)/4, 256, 0, stream>>>(y1h, g_d, b_d, W_dec2, stats + 256, out, N);
}

// Round 9
// 464.168 us; speedup vs baseline: 1.0295x; 1.0295x over previous
//
#include <hip/hip_runtime.h>

#define DD 128

typedef _Float16 f16x8 __attribute__((ext_vector_type(8)));
typedef unsigned short u16x8 __attribute__((ext_vector_type(8)));
typedef unsigned short u16x4 __attribute__((ext_vector_type(4)));
typedef float f32x4 __attribute__((ext_vector_type(4)));

__device__ __forceinline__ float sigmoidf_(float v){ return 1.f/(1.f+__expf(-v)); }
__device__ __forceinline__ float tanhf_(float v){
  float e2 = __expf(2.f*v);
  return 1.f - 2.f/(e2 + 1.f);
}
__device__ __forceinline__ float h2f(unsigned short u){
  _Float16 h; __builtin_memcpy(&h, &u, 2); return (float)h;
}
__device__ __forceinline__ unsigned short f2h(float v){
  _Float16 h = (_Float16)v; unsigned short u; __builtin_memcpy(&u, &h, 2); return u;
}
__device__ __forceinline__ f16x8 splat8(_Float16 v){
  return (f16x8){v,v,v,v,v,v,v,v};
}

// drain remaining edges [i,e) for one node, accumulating 8 features at octet q
// packed-fp16 inner math, fp32 flush per batch
__device__ __forceinline__ void gather_drain(const unsigned short* __restrict__ phc,
        const int2* __restrict__ csr, int i, int e, int q, float* acc){
  for (; i + 8 <= e; i += 8){
    int2 ed[8]; u16x8 R[8];
    #pragma unroll
    for (int u = 0; u < 8; u++) ed[u] = csr[i+u];
    #pragma unroll
    for (int u = 0; u < 8; u++) R[u] = *(const u16x8*)(phc + (size_t)ed[u].x*DD + q*8);
    f16x8 s = (f16x8){0,0,0,0,0,0,0,0};
    #pragma unroll
    for (int u = 0; u < 8; u++){
      union { int i; float f; } c; c.i = ed[u].y;
      s += *(const f16x8*)&R[u] * splat8((_Float16)c.f);
    }
    #pragma unroll
    for (int t = 0; t < 8; t++) acc[t] += (float)s[t];
  }
  if (i + 4 <= e){
    int2 ed[4]; u16x8 R[4];
    #pragma unroll
    for (int u = 0; u < 4; u++) ed[u] = csr[i+u];
    #pragma unroll
    for (int u = 0; u < 4; u++) R[u] = *(const u16x8*)(phc + (size_t)ed[u].x*DD + q*8);
    f16x8 s = (f16x8){0,0,0,0,0,0,0,0};
    #pragma unroll
    for (int u = 0; u < 4; u++){
      union { int i; float f; } c; c.i = ed[u].y;
      s += *(const f16x8*)&R[u] * splat8((_Float16)c.f);
    }
    #pragma unroll
    for (int t = 0; t < 8; t++) acc[t] += (float)s[t];
    i += 4;
  }
  for (; i < e; i++){
    int2 ed = csr[i];
    union { int i; float f; } c; c.i = ed.y;
    u16x8 R = *(const u16x8*)(phc + (size_t)ed.x*DD + q*8);
    #pragma unroll
    for (int t = 0; t < 8; t++)
      acc[t] = fmaf(c.f, h2f((unsigned short)R[t]), acc[t]);
  }
}

// ---------- fused pre-pass 1: weight prep  ∪  encoder matvec+stats  ∪  dst histogram ----------
#define PREP_B 416   // (2*384*128 + 64*128)/256
__global__ void __launch_bounds__(256) k_pre1(
        const float* __restrict__ W_ih, const float* __restrict__ W_hh,
        const float* __restrict__ W_dec, const float* __restrict__ x,
        const float* __restrict__ W_enc, const int* __restrict__ dst,
        unsigned short* __restrict__ Wih_h, unsigned short* __restrict__ Whh_h,
        unsigned short* __restrict__ Wd_h, unsigned short* __restrict__ h0,
        float* __restrict__ stats, int* __restrict__ counts, int N, int E){
  const int tid = threadIdx.x;
  const int gb = blockIdx.x;
  const int TOT = 384*128;
  if (gb < PREP_B){
    int idx = gb*256 + tid;
    if (idx < 2*TOT){
      const float* W = (idx < TOT) ? W_ih : W_hh;
      unsigned short* D = (idx < TOT) ? Wih_h : Whh_h;
      int fi = (idx < TOT) ? idx : idx - TOT;
      int t = fi & 7;
      int l = (fi >> 3) & 63;
      int ks = (fi >> 9) & 3;
      int nt = fi >> 11;
      int fg = nt / 3, gate = nt % 3;
      int j = gate*128 + fg*16 + (l & 15);
      int k = ks*32 + ((l >> 4) & 3)*8 + t;
      D[fi] = f2h(W[j*128 + k]);
    } else if (idx < 2*TOT + 64*128){
      int fi2 = idx - 2*TOT;
      int t  = fi2 & 7;
      int l  = (fi2 >> 3) & 63;
      int ks = (fi2 >> 9) & 3;
      int jt = fi2 >> 11;
      int j = jt*16 + (l & 15);
      int k = ks*32 + ((l >> 4) & 3)*8 + t;
      Wd_h[fi2] = f2h(W_dec[j*128 + k]);
    }
  } else if (gb < PREP_B + 256){
    const int b = gb - PREP_B;
    const int f = tid & 127;
    const int sub = tid >> 7;
    const float w0 = W_enc[f*3], w1 = W_enc[f*3+1], w2 = W_enc[f*3+2];
    const int chunk = (N + 255) / 256;
    const int n0 = b * chunk;
    const int n1 = (n0 + chunk < N) ? (n0 + chunk) : N;
    float s = 0.f, q = 0.f;
    for (int n = n0 + sub; n < n1; n += 2){
      float x0 = x[n*3], x1 = x[n*3+1], x2 = x[n*3+2];
      float h = x0*w0 + x1*w1 + x2*w2;
      unsigned short hu = f2h(h);
      float hq = h2f(hu);
      h0[(size_t)n*DD + f] = hu;
      s += hq; q += hq*hq;
    }
    atomicAdd(&stats[f], s);
    atomicAdd(&stats[DD+f], q);
  } else {
    int e = (gb - PREP_B - 256)*256 + tid;
    if (e < E) atomicAdd(&counts[dst[e]], 1);
  }
}

// ---------- scan chain ----------
__global__ void __launch_bounds__(256) k_scan_part(const int* __restrict__ counts,
                                                   int* __restrict__ partials, int N){
  int i = blockIdx.x*256 + threadIdx.x;
  int v = (i < N) ? counts[i] : 0;
  #pragma unroll
  for (int off = 32; off > 0; off >>= 1) v += __shfl_down(v, off, 64);
  __shared__ int red[4];
  if ((threadIdx.x & 63) == 0) red[threadIdx.x >> 6] = v;
  __syncthreads();
  if (threadIdx.x == 0) partials[blockIdx.x] = red[0]+red[1]+red[2]+red[3];
}

__global__ void __launch_bounds__(256) k_scan_mid(int* __restrict__ partials, int P,
                                                  int* __restrict__ offsets, int N){
  __shared__ int lds[4];
  __shared__ int carry_s;
  const int lane = threadIdx.x & 63, wid = threadIdx.x >> 6;
  if (threadIdx.x == 0) carry_s = 0;
  __syncthreads();
  for (int base = 0; base < P; base += 256){
    int i = base + threadIdx.x;
    int v = (i < P) ? partials[i] : 0;
    int orig = v;
    #pragma unroll
    for (int off = 1; off < 64; off <<= 1){
      int u = __shfl_up(v, off, 64);
      if (lane >= off) v += u;
    }
    if (lane == 63) lds[wid] = v;
    __syncthreads();
    if (threadIdx.x == 0){
      int s = carry_s;
      for (int k = 0; k < 4; k++){ int t = lds[k]; lds[k] = s; s += t; }
      carry_s = s;
    }
    __syncthreads();
    int excl = v - orig + lds[wid];
    if (i < P) partials[i] = excl;
    __syncthreads();
  }
  if (threadIdx.x == 0) offsets[N] = carry_s;
}

__global__ void __launch_bounds__(256) k_scan_expand(const int* __restrict__ counts,
        const int* __restrict__ partials, int* __restrict__ offsets,
        int* __restrict__ cursors, int N){
  int i = blockIdx.x*256 + threadIdx.x;
  int v = (i < N) ? counts[i] : 0;
  int orig = v;
  const int lane = threadIdx.x & 63, wid = threadIdx.x >> 6;
  #pragma unroll
  for (int off = 1; off < 64; off <<= 1){
    int u = __shfl_up(v, off, 64);
    if (lane >= off) v += u;
  }
  __shared__ int lds[4];
  if (lane == 63) lds[wid] = v;
  __syncthreads();
  int wbase = 0;
  for (int k = 0; k < wid; k++) wbase += lds[k];
  int excl = partials[blockIdx.x] + wbase + v - orig;
  if (i < N){ offsets[i] = excl; cursors[i] = excl; }
}

// ---------- fused pre-pass 2: vectorized BN+ReLU apply  ∪  CSR fill ----------
__global__ void __launch_bounds__(256) k_pre2(
        const unsigned short* __restrict__ h0, const float* __restrict__ gamma,
        const float* __restrict__ beta, const float* __restrict__ stats,
        unsigned short* __restrict__ ph,
        const int* __restrict__ src, const int* __restrict__ dst,
        const float* __restrict__ norm, int* __restrict__ cursors,
        int2* __restrict__ csr, int N, int E, int AB8){
  const int tid = threadIdx.x;
  if ((int)blockIdx.x < AB8){
    int idx8 = (blockIdx.x*256 + tid) * 8;
    if (idx8 >= N*DD) return;
    int f0 = idx8 & (DD-1);
    u16x8 hv = *(const u16x8*)(h0 + idx8);
    float4 ga = *(const float4*)(gamma + f0);
    float4 gb = *(const float4*)(gamma + f0 + 4);
    float4 ba = *(const float4*)(beta + f0);
    float4 bb = *(const float4*)(beta + f0 + 4);
    float4 sa = *(const float4*)(stats + f0);
    float4 sb = *(const float4*)(stats + f0 + 4);
    float4 qa = *(const float4*)(stats + DD + f0);
    float4 qb = *(const float4*)(stats + DD + f0 + 4);
    float g[8] = {ga.x,ga.y,ga.z,ga.w,gb.x,gb.y,gb.z,gb.w};
    float b[8] = {ba.x,ba.y,ba.z,ba.w,bb.x,bb.y,bb.z,bb.w};
    float s[8] = {sa.x,sa.y,sa.z,sa.w,sb.x,sb.y,sb.z,sb.w};
    float q[8] = {qa.x,qa.y,qa.z,qa.w,qb.x,qb.y,qb.z,qb.w};
    const float invN = 1.f / (float)N;
    u16x8 outv;
    #pragma unroll
    for (int t = 0; t < 8; t++){
      float mu = s[t] * invN;
      float var = q[t] * invN - mu*mu;
      float v = (h2f(hv[t]) - mu) * rsqrtf(var + 1e-5f) * g[t] + b[t];
      outv[t] = f2h(fmaxf(v, 0.f));
    }
    *(u16x8*)(ph + idx8) = outv;
  } else {
    int e = ((int)blockIdx.x - AB8)*256 + tid;
    if (e >= E) return;
    int p = atomicAdd(&cursors[dst[e]], 1);
    union { float f; int i; } c; c.f = norm[e];
    csr[p] = make_int2(src[e], c.i);
  }
}

// ---------- fused layer (0..3): 256 thr / 32 nodes, packed paired gather -> LDS -> MFMA ----------
__global__ void __launch_bounds__(256, 4) k_layer(
        const unsigned short* __restrict__ phc,
        unsigned short* __restrict__ phn,
        unsigned short* __restrict__ agg_out,
        const int* __restrict__ offsets, const int2* __restrict__ csr,
        const unsigned short* __restrict__ Wih_h, const unsigned short* __restrict__ Whh_h,
        const float* __restrict__ b_ih, const float* __restrict__ b_hh, int N){
  __shared__ unsigned short s_a[32*DD];
  const int tid = threadIdx.x;
  const int n0 = blockIdx.x * 32;

  // ---- phase 1: paired gather — group (tid>>4) owns nodes m and m+16 concurrently ----
  {
    const int m = tid >> 4;      // 0..15
    const int q = tid & 15;      // feature octet
    const int nA = n0 + m;
    const int nB = n0 + 16 + m;
    float aA[8], aB[8];
    #pragma unroll
    for (int t = 0; t < 8; t++){ aA[t] = 0.f; aB[t] = 0.f; }
    int iA = 0, eA = 0, iB = 0, eB = 0;
    if (nA < N){ iA = offsets[nA]; eA = offsets[nA+1]; }
    if (nB < N){ iB = offsets[nB]; eB = offsets[nB+1]; }

    // joint hot loop: 4 edges of A + 4 edges of B in flight; packed-fp16 math
    while (iA + 4 <= eA && iB + 4 <= eB){
      int2 edA[4], edB[4];
      #pragma unroll
      for (int u = 0; u < 4; u++){ edA[u] = csr[iA+u]; edB[u] = csr[iB+u]; }
      u16x8 RA[4], RB[4];
      #pragma unroll
      for (int u = 0; u < 4; u++){
        RA[u] = *(const u16x8*)(phc + (size_t)edA[u].x*DD + q*8);
        RB[u] = *(const u16x8*)(phc + (size_t)edB[u].x*DD + q*8);
      }
      f16x8 sA = (f16x8){0,0,0,0,0,0,0,0};
      f16x8 sB = (f16x8){0,0,0,0,0,0,0,0};
      #pragma unroll
      for (int u = 0; u < 4; u++){
        union { int i; float f; } cA, cB; cA.i = edA[u].y; cB.i = edB[u].y;
        sA += *(const f16x8*)&RA[u] * splat8((_Float16)cA.f);
        sB += *(const f16x8*)&RB[u] * splat8((_Float16)cB.f);
      }
      #pragma unroll
      for (int t = 0; t < 8; t++){
        aA[t] += (float)sA[t];
        aB[t] += (float)sB[t];
      }
      iA += 4; iB += 4;
    }
    gather_drain(phc, csr, iA, eA, q, aA);
    gather_drain(phc, csr, iB, eB, q, aB);

    u16x8 vA, vB;
    #pragma unroll
    for (int t = 0; t < 8; t++){ vA[t] = f2h(aA[t]); vB[t] = f2h(aB[t]); }
    if (nA < N) *(u16x8*)(agg_out + (size_t)nA*DD + q*8) = vA;
    if (nB < N) *(u16x8*)(agg_out + (size_t)nB*DD + q*8) = vB;
    const int ccA = q ^ (m & 7);
    *(u16x8*)(s_a + m*DD + ccA*8) = vA;
    *(u16x8*)(s_a + (16+m)*DD + ccA*8) = vB;   // (16+m)&7 == m&7
  }
  __syncthreads();   // the only barrier: LDS A-frags ready

  // ---- phase 2+3 per feature group (wave w -> fg w*2+g), 2 node-tiles ----
  const int w = tid >> 6, l = tid & 63, ar = l & 15, aq = l >> 4;
  int r0 = n0 + ar;      if (r0 >= N) r0 = N-1;
  int r1 = n0 + 16 + ar; if (r1 >= N) r1 = N-1;
  const size_t p0 = (size_t)r0*DD + aq*8;
  const size_t p1 = (size_t)r1*DD + aq*8;
  const int sw = ar & 7;

  for (int g = 0; g < 2; g++){
    const int fg = w*2 + g;
    f32x4 acc_i[2][3], acc_h[2][3];
    #pragma unroll
    for (int ta = 0; ta < 2; ta++)
      #pragma unroll
      for (int t = 0; t < 3; t++){
        acc_i[ta][t] = (f32x4){0.f,0.f,0.f,0.f};
        acc_h[ta][t] = (f32x4){0.f,0.f,0.f,0.f};
      }

    #pragma unroll
    for (int ks = 0; ks < 4; ks++){
      const int c = (ks*4 + aq) ^ sw;
      f16x8 ih0 = *(const f16x8*)(s_a + ar*DD       + c*8);
      f16x8 ih1 = *(const f16x8*)(s_a + (16+ar)*DD  + c*8);
      f16x8 hh0 = *(const f16x8*)(phc + p0 + ks*32);
      f16x8 hh1 = *(const f16x8*)(phc + p1 + ks*32);
      #pragma unroll
      for (int t = 0; t < 3; t++){
        size_t bo = ((size_t)((fg*3 + t)*4 + ks)*64 + l)*8;
        f16x8 bih = *(const f16x8*)(Wih_h + bo);
        f16x8 bhh = *(const f16x8*)(Whh_h + bo);
        acc_i[0][t] = __builtin_amdgcn_mfma_f32_16x16x32_f16(ih0, bih, acc_i[0][t], 0, 0, 0);
        acc_i[1][t] = __builtin_amdgcn_mfma_f32_16x16x32_f16(ih1, bih, acc_i[1][t], 0, 0, 0);
        acc_h[0][t] = __builtin_amdgcn_mfma_f32_16x16x32_f16(hh0, bhh, acc_h[0][t], 0, 0, 0);
        acc_h[1][t] = __builtin_amdgcn_mfma_f32_16x16x32_f16(hh1, bhh, acc_h[1][t], 0, 0, 0);
      }
    }

    const int f = fg*16 + ar;
    const float bir = b_ih[f], biz = b_ih[128+f], bin_ = b_ih[256+f];
    const float bhr = b_hh[f], bhz = b_hh[128+f], bhn = b_hh[256+f];
    #pragma unroll
    for (int ta = 0; ta < 2; ta++){
      #pragma unroll
      for (int r = 0; r < 4; r++){
        int n = n0 + ta*16 + aq*4 + r;
        if (n < N){
          float sir = acc_i[ta][0][r] + bir, shr = acc_h[ta][0][r] + bhr;
          float siz = acc_i[ta][1][r] + biz, shz = acc_h[ta][1][r] + bhz;
          float sin_ = acc_i[ta][2][r] + bin_, shn = acc_h[ta][2][r] + bhn;
          float rr = sigmoidf_(sir + shr);
          float zz = sigmoidf_(siz + shz);
          float nn = tanhf_(sin_ + rr*shn);
          size_t o = (size_t)n*DD + f;
          float hp = h2f(phc[o]);
          float h = (1.f - zz)*nn + zz*hp;
          phn[o] = f2h(h);
        }
      }
    }
  }
}

// ---------- decoder stage 1: 16 nodes/block, gather + layer-sum -> fp16 LDS -> MFMA matvec ----------
__global__ void __launch_bounds__(256, 8) k_dec1(const unsigned short* __restrict__ hbn,
        const unsigned short* __restrict__ aggs, size_t NF,
        const unsigned short* __restrict__ ph5,
        const int* __restrict__ offsets, const int2* __restrict__ csr,
        const unsigned short* __restrict__ Wd_h, unsigned short* __restrict__ y1,
        float* __restrict__ stats_d, int N){
  __shared__ unsigned short zs[16*DD];
  __shared__ unsigned short stage[16*64];
  const int tid = threadIdx.x;
  const int n0 = blockIdx.x * 16;

  // ---- phase A: gather + layer-sum ----
  {
    const int m = tid >> 4;      // node slot 0..15
    const int q = tid & 15;      // feature octet
    const int n = n0 + m;
    float acc[8];
    #pragma unroll
    for (int t = 0; t < 8; t++) acc[t] = 0.f;
    if (n < N){
      size_t o = (size_t)n*DD + q*8;
      u16x8 hb = *(const u16x8*)(hbn + o);
      #pragma unroll
      for (int t = 0; t < 8; t++) acc[t] = h2f(hb[t]);
      #pragma unroll
      for (int l = 0; l < 4; l++){
        u16x8 ag = *(const u16x8*)(aggs + l*NF + o);
        #pragma unroll
        for (int t = 0; t < 8; t++) acc[t] += h2f(ag[t]);
      }
      gather_drain(ph5, csr, offsets[n], offsets[n+1], q, acc);
    }
    u16x8 vh;
    #pragma unroll
    for (int t = 0; t < 8; t++) vh[t] = f2h(acc[t] * (1.f/6.f));
    const int cc = q ^ (m & 7);
    *(u16x8*)(zs + m*DD + cc*8) = vh;
  }
  __syncthreads();

  // ---- phase B: MFMA matvec z(16x128) x Wd^T(128x64), wave w -> j-tile w ----
  const int w = tid >> 6, l = tid & 63, ar = l & 15, aq = l >> 4;
  const int sw = ar & 7;
  f32x4 acc = (f32x4){0.f,0.f,0.f,0.f};
  #pragma unroll
  for (int ks = 0; ks < 4; ks++){
    const int c = (ks*4 + aq) ^ sw;
    f16x8 a = *(const f16x8*)(zs + ar*DD + c*8);
    f16x8 b = *(const f16x8*)(Wd_h + ((size_t)(w*4 + ks)*64 + l)*8);
    acc = __builtin_amdgcn_mfma_f32_16x16x32_f16(a, b, acc, 0, 0, 0);
  }
  float s = 0.f, q2 = 0.f;
  #pragma unroll
  for (int r = 0; r < 4; r++){
    int n = n0 + aq*4 + r;
    float v = acc[r];
    if (n < N){
      stage[(aq*4 + r)*64 + w*16 + ar] = f2h(v);
      s += v; q2 += v*v;
    }
  }
  s  += __shfl_xor(s, 16, 64);  s  += __shfl_xor(s, 32, 64);
  q2 += __shfl_xor(q2, 16, 64); q2 += __shfl_xor(q2, 32, 64);
  if (aq == 0){
    float* st = stats_d + (size_t)(blockIdx.x & 7)*128;
    atomicAdd(&st[w*16 + ar], s);
    atomicAdd(&st[64 + w*16 + ar], q2);
  }
  __syncthreads();
  // ---- coalesced fp16 y1 write: 256 threads x 4 u16 = 16*64 ----
  {
    int idx = tid * 4;
    int n = n0 + (idx >> 6);
    if (n < N)
      *(u16x4*)(y1 + (size_t)n0*64 + idx) = *(const u16x4*)(stage + idx);
  }
}

// ---------- decoder stage 2: sum stats copies, bn + relu + dot ----------
__global__ void __launch_bounds__(256) k_dec2(const unsigned short* __restrict__ y1,
        const float* __restrict__ gamma, const float* __restrict__ beta,
        const float* __restrict__ W_dec2, const float* __restrict__ stats_d,
        float* __restrict__ out, int N){
  const int j = threadIdx.x & 63;
  const int g = threadIdx.x >> 6;
  const int n = blockIdx.x*4 + g;
  if (n >= N) return;
  float ssum = 0.f, qsum = 0.f;
  #pragma unroll
  for (int c = 0; c < 8; c++){
    ssum += stats_d[c*128 + j];
    qsum += stats_d[c*128 + 64 + j];
  }
  float invN = 1.f / (float)N;
  float mu = ssum * invN;
  float var = qsum * invN - mu*mu;
  float v = (h2f(y1[(size_t)n*64 + j]) - mu) * rsqrtf(var + 1e-5f) * gamma[j] + beta[j];
  v = fmaxf(v, 0.f) * W_dec2[j];
  for (int off = 32; off > 0; off >>= 1) v += __shfl_down(v, off, 64);
  if (j == 0) out[n] = v;
}

extern "C" void kernel_launch(void* const* d_in, const int* in_sizes, int n_in,
                              void* d_out, int out_size, void* d_ws, size_t ws_size,
                              hipStream_t stream) {
  const int N = in_sizes[0] / 3;
  const int E = in_sizes[1] / 2;
  const int P = (N + 255) / 256;
  const int HIST_B = (E + 255) / 256;
  const int AB8 = (N*DD/8 + 255) / 256;

  const float* x     = (const float*)d_in[0];
  const int*   ei    = (const int*)d_in[1];
  const int*   src   = ei;
  const int*   dst   = ei + E;
  const float* norm  = (const float*)d_in[2];
  const float* W_enc = (const float*)d_in[3];
  const float* g_e   = (const float*)d_in[4];
  const float* b_e   = (const float*)d_in[5];
  const float* W_ih  = (const float*)d_in[6];
  const float* W_hh  = (const float*)d_in[7];
  const float* b_ih  = (const float*)d_in[8];
  const float* b_hh  = (const float*)d_in[9];
  const float* W_dec = (const float*)d_in[10];
  const float* g_d   = (const float*)d_in[11];
  const float* b_d   = (const float*)d_in[12];
  const float* W_dec2= (const float*)d_in[13];
  float* out = (float*)d_out;

  float* ws = (float*)d_ws;
  const size_t NF = (size_t)N * DD;
  float* scr    = ws;                        // NF fp32 region: h0 (fp16, pre) / y1 (fp16, decode)
  unsigned short* h0h = (unsigned short*)scr;
  unsigned short* y1h = (unsigned short*)scr; // h0 dead after k_pre2
  float* stats  = scr + NF;                  // 256 enc + 1024 dec
  float* Wt_dec = stats + 1280;              // region: 64*128 floats (Wd_h uses first 16KB)
  unsigned short* Wd_h  = (unsigned short*)Wt_dec;
  unsigned short* Wih_h = (unsigned short*)(Wt_dec + 64*128);
  unsigned short* Whh_h = Wih_h + 384*128;
  unsigned short* ph_A  = Whh_h + 384*128;   // NF ushorts each; ph_A = post-BN h (pristine, = hbn)
  unsigned short* ph_B  = ph_A + NF;
  unsigned short* ph_C  = ph_B + NF;
  unsigned short* aggs  = ph_C + NF;         // 4 * NF ushorts (layers 0..3)
  int*   counts  = (int*)(aggs + 4*NF);      // N
  int*   offsets = counts + N;               // N+1
  int*   cursors = offsets + N + 1;          // N
  int*   partials= cursors + N;              // P
  int2*  csr     = (int2*)(partials + P);    // E int2 (src, norm-bits)

  hipMemsetAsync(stats, 0, 1280*sizeof(float), stream);
  hipMemsetAsync(counts, 0, (size_t)N*sizeof(int), stream);

  k_pre1<<<PREP_B + 256 + HIST_B, 256, 0, stream>>>(
      W_ih, W_hh, W_dec, x, W_enc, dst,
      Wih_h, Whh_h, Wd_h, h0h, stats, counts, N, E);
  k_scan_part<<<P, 256, 0, stream>>>(counts, partials, N);
  k_scan_mid<<<1, 256, 0, stream>>>(partials, P, offsets, N);
  k_scan_expand<<<P, 256, 0, stream>>>(counts, partials, offsets, cursors, N);
  k_pre2<<<AB8 + HIST_B, 256, 0, stream>>>(
      h0h, g_e, b_e, stats, ph_A,
      src, dst, norm, cursors, csr, N, E, AB8);

  // layers ping-pong through B/C, leaving ph_A (post-BN h) pristine for the decoder
  const int UB = (N + 31) / 32;
  k_layer<<<UB, 256, 0, stream>>>(ph_A, ph_B, aggs + (size_t)0*NF, offsets, csr,
                                  Wih_h, Whh_h, b_ih, b_hh, N);
  k_layer<<<UB, 256, 0, stream>>>(ph_B, ph_C, aggs + (size_t)1*NF, offsets, csr,
                                  Wih_h, Whh_h, b_ih, b_hh, N);
  k_layer<<<UB, 256, 0, stream>>>(ph_C, ph_B, aggs + (size_t)2*NF, offsets, csr,
                                  Wih_h, Whh_h, b_ih, b_hh, N);
  k_layer<<<UB, 256, 0, stream>>>(ph_B, ph_C, aggs + (size_t)3*NF, offsets, csr,
                                  Wih_h, Whh_h, b_ih, b_hh, N);

  k_dec1<<<(N + 15)/16, 256, 0, stream>>>(ph_A, aggs, NF, ph_C, offsets, csr,
                                          Wd_h, y1h, stats + 256, N);
  k_dec2<<<(N + 3)/4, 256, 0, stream>>>(y1h, g_d, b_d, W_dec2, stats + 256, out, N);
}

// Round 10
// 461.955 us; speedup vs baseline: 1.0344x; 1.0048x over previous
//
#include <hip/hip_runtime.h>

#define DD 128

typedef _Float16 f16x8 __attribute__((ext_vector_type(8)));
typedef unsigned short u16x8 __attribute__((ext_vector_type(8)));
typedef unsigned short u16x4 __attribute__((ext_vector_type(4)));
typedef float f32x4 __attribute__((ext_vector_type(4)));

__device__ __forceinline__ float sigmoidf_(float v){ return 1.f/(1.f+__expf(-v)); }
__device__ __forceinline__ float tanhf_(float v){
  float e2 = __expf(2.f*v);
  return 1.f - 2.f/(e2 + 1.f);
}
__device__ __forceinline__ float h2f(unsigned short u){
  _Float16 h; __builtin_memcpy(&h, &u, 2); return (float)h;
}
__device__ __forceinline__ unsigned short f2h(float v){
  _Float16 h = (_Float16)v; unsigned short u; __builtin_memcpy(&u, &h, 2); return u;
}
__device__ __forceinline__ f16x8 splat8(_Float16 v){
  return (f16x8){v,v,v,v,v,v,v,v};
}

// drain remaining edges [i,e) for one node, accumulating 8 features at octet q
// packed-fp16 inner math, fp32 flush per batch
__device__ __forceinline__ void gather_drain(const unsigned short* __restrict__ phc,
        const int2* __restrict__ csr, int i, int e, int q, float* acc){
  for (; i + 8 <= e; i += 8){
    int2 ed[8]; u16x8 R[8];
    #pragma unroll
    for (int u = 0; u < 8; u++) ed[u] = csr[i+u];
    #pragma unroll
    for (int u = 0; u < 8; u++) R[u] = *(const u16x8*)(phc + (size_t)ed[u].x*DD + q*8);
    f16x8 s = (f16x8){0,0,0,0,0,0,0,0};
    #pragma unroll
    for (int u = 0; u < 8; u++){
      union { int i; float f; } c; c.i = ed[u].y;
      s += *(const f16x8*)&R[u] * splat8((_Float16)c.f);
    }
    #pragma unroll
    for (int t = 0; t < 8; t++) acc[t] += (float)s[t];
  }
  if (i + 4 <= e){
    int2 ed[4]; u16x8 R[4];
    #pragma unroll
    for (int u = 0; u < 4; u++) ed[u] = csr[i+u];
    #pragma unroll
    for (int u = 0; u < 4; u++) R[u] = *(const u16x8*)(phc + (size_t)ed[u].x*DD + q*8);
    f16x8 s = (f16x8){0,0,0,0,0,0,0,0};
    #pragma unroll
    for (int u = 0; u < 4; u++){
      union { int i; float f; } c; c.i = ed[u].y;
      s += *(const f16x8*)&R[u] * splat8((_Float16)c.f);
    }
    #pragma unroll
    for (int t = 0; t < 8; t++) acc[t] += (float)s[t];
    i += 4;
  }
  for (; i < e; i++){
    int2 ed = csr[i];
    union { int i; float f; } c; c.i = ed.y;
    u16x8 R = *(const u16x8*)(phc + (size_t)ed.x*DD + q*8);
    #pragma unroll
    for (int t = 0; t < 8; t++)
      acc[t] = fmaf(c.f, h2f((unsigned short)R[t]), acc[t]);
  }
}

// ---------- fused pre-pass 1: weight prep  ∪  encoder matvec+stats  ∪  dst histogram ----------
#define PREP_B 416   // (2*384*128 + 64*128)/256
__global__ void __launch_bounds__(256) k_pre1(
        const float* __restrict__ W_ih, const float* __restrict__ W_hh,
        const float* __restrict__ W_dec, const float* __restrict__ x,
        const float* __restrict__ W_enc, const int* __restrict__ dst,
        unsigned short* __restrict__ Wih_h, unsigned short* __restrict__ Whh_h,
        unsigned short* __restrict__ Wd_h, unsigned short* __restrict__ h0,
        float* __restrict__ stats, int* __restrict__ counts, int N, int E){
  const int tid = threadIdx.x;
  const int gb = blockIdx.x;
  const int TOT = 384*128;
  if (gb < PREP_B){
    int idx = gb*256 + tid;
    if (idx < 2*TOT){
      const float* W = (idx < TOT) ? W_ih : W_hh;
      unsigned short* D = (idx < TOT) ? Wih_h : Whh_h;
      int fi = (idx < TOT) ? idx : idx - TOT;
      int t = fi & 7;
      int l = (fi >> 3) & 63;
      int ks = (fi >> 9) & 3;
      int nt = fi >> 11;
      int fg = nt / 3, gate = nt % 3;
      int j = gate*128 + fg*16 + (l & 15);
      int k = ks*32 + ((l >> 4) & 3)*8 + t;
      D[fi] = f2h(W[j*128 + k]);
    } else if (idx < 2*TOT + 64*128){
      int fi2 = idx - 2*TOT;
      int t  = fi2 & 7;
      int l  = (fi2 >> 3) & 63;
      int ks = (fi2 >> 9) & 3;
      int jt = fi2 >> 11;
      int j = jt*16 + (l & 15);
      int k = ks*32 + ((l >> 4) & 3)*8 + t;
      Wd_h[fi2] = f2h(W_dec[j*128 + k]);
    }
  } else if (gb < PREP_B + 256){
    const int b = gb - PREP_B;
    const int f = tid & 127;
    const int sub = tid >> 7;
    const float w0 = W_enc[f*3], w1 = W_enc[f*3+1], w2 = W_enc[f*3+2];
    const int chunk = (N + 255) / 256;
    const int n0 = b * chunk;
    const int n1 = (n0 + chunk < N) ? (n0 + chunk) : N;
    float s = 0.f, q = 0.f;
    for (int n = n0 + sub; n < n1; n += 2){
      float x0 = x[n*3], x1 = x[n*3+1], x2 = x[n*3+2];
      float h = x0*w0 + x1*w1 + x2*w2;
      unsigned short hu = f2h(h);
      float hq = h2f(hu);
      h0[(size_t)n*DD + f] = hu;
      s += hq; q += hq*hq;
    }
    atomicAdd(&stats[f], s);
    atomicAdd(&stats[DD+f], q);
  } else {
    int e = (gb - PREP_B - 256)*256 + tid;
    if (e < E) atomicAdd(&counts[dst[e]], 1);
  }
}

// ---------- scan chain ----------
__global__ void __launch_bounds__(256) k_scan_part(const int* __restrict__ counts,
                                                   int* __restrict__ partials, int N){
  int i = blockIdx.x*256 + threadIdx.x;
  int v = (i < N) ? counts[i] : 0;
  #pragma unroll
  for (int off = 32; off > 0; off >>= 1) v += __shfl_down(v, off, 64);
  __shared__ int red[4];
  if ((threadIdx.x & 63) == 0) red[threadIdx.x >> 6] = v;
  __syncthreads();
  if (threadIdx.x == 0) partials[blockIdx.x] = red[0]+red[1]+red[2]+red[3];
}

__global__ void __launch_bounds__(256) k_scan_mid(int* __restrict__ partials, int P,
                                                  int* __restrict__ offsets, int N){
  __shared__ int lds[4];
  __shared__ int carry_s;
  const int lane = threadIdx.x & 63, wid = threadIdx.x >> 6;
  if (threadIdx.x == 0) carry_s = 0;
  __syncthreads();
  for (int base = 0; base < P; base += 256){
    int i = base + threadIdx.x;
    int v = (i < P) ? partials[i] : 0;
    int orig = v;
    #pragma unroll
    for (int off = 1; off < 64; off <<= 1){
      int u = __shfl_up(v, off, 64);
      if (lane >= off) v += u;
    }
    if (lane == 63) lds[wid] = v;
    __syncthreads();
    if (threadIdx.x == 0){
      int s = carry_s;
      for (int k = 0; k < 4; k++){ int t = lds[k]; lds[k] = s; s += t; }
      carry_s = s;
    }
    __syncthreads();
    int excl = v - orig + lds[wid];
    if (i < P) partials[i] = excl;
    __syncthreads();
  }
  if (threadIdx.x == 0) offsets[N] = carry_s;
}

__global__ void __launch_bounds__(256) k_scan_expand(const int* __restrict__ counts,
        const int* __restrict__ partials, int* __restrict__ offsets,
        int* __restrict__ cursors, int N){
  int i = blockIdx.x*256 + threadIdx.x;
  int v = (i < N) ? counts[i] : 0;
  int orig = v;
  const int lane = threadIdx.x & 63, wid = threadIdx.x >> 6;
  #pragma unroll
  for (int off = 1; off < 64; off <<= 1){
    int u = __shfl_up(v, off, 64);
    if (lane >= off) v += u;
  }
  __shared__ int lds[4];
  if (lane == 63) lds[wid] = v;
  __syncthreads();
  int wbase = 0;
  for (int k = 0; k < wid; k++) wbase += lds[k];
  int excl = partials[blockIdx.x] + wbase + v - orig;
  if (i < N){ offsets[i] = excl; cursors[i] = excl; }
}

// ---------- fused pre-pass 2: vectorized BN+ReLU apply  ∪  CSR fill ----------
__global__ void __launch_bounds__(256) k_pre2(
        const unsigned short* __restrict__ h0, const float* __restrict__ gamma,
        const float* __restrict__ beta, const float* __restrict__ stats,
        unsigned short* __restrict__ ph,
        const int* __restrict__ src, const int* __restrict__ dst,
        const float* __restrict__ norm, int* __restrict__ cursors,
        int2* __restrict__ csr, int N, int E, int AB8){
  const int tid = threadIdx.x;
  if ((int)blockIdx.x < AB8){
    int idx8 = (blockIdx.x*256 + tid) * 8;
    if (idx8 >= N*DD) return;
    int f0 = idx8 & (DD-1);
    u16x8 hv = *(const u16x8*)(h0 + idx8);
    float4 ga = *(const float4*)(gamma + f0);
    float4 gb = *(const float4*)(gamma + f0 + 4);
    float4 ba = *(const float4*)(beta + f0);
    float4 bb = *(const float4*)(beta + f0 + 4);
    float4 sa = *(const float4*)(stats + f0);
    float4 sb = *(const float4*)(stats + f0 + 4);
    float4 qa = *(const float4*)(stats + DD + f0);
    float4 qb = *(const float4*)(stats + DD + f0 + 4);
    float g[8] = {ga.x,ga.y,ga.z,ga.w,gb.x,gb.y,gb.z,gb.w};
    float b[8] = {ba.x,ba.y,ba.z,ba.w,bb.x,bb.y,bb.z,bb.w};
    float s[8] = {sa.x,sa.y,sa.z,sa.w,sb.x,sb.y,sb.z,sb.w};
    float q[8] = {qa.x,qa.y,qa.z,qa.w,qb.x,qb.y,qb.z,qb.w};
    const float invN = 1.f / (float)N;
    u16x8 outv;
    #pragma unroll
    for (int t = 0; t < 8; t++){
      float mu = s[t] * invN;
      float var = q[t] * invN - mu*mu;
      float v = (h2f(hv[t]) - mu) * rsqrtf(var + 1e-5f) * g[t] + b[t];
      outv[t] = f2h(fmaxf(v, 0.f));
    }
    *(u16x8*)(ph + idx8) = outv;
  } else {
    int e = ((int)blockIdx.x - AB8)*256 + tid;
    if (e >= E) return;
    int p = atomicAdd(&cursors[dst[e]], 1);
    union { float f; int i; } c; c.f = norm[e];
    csr[p] = make_int2(src[e], c.i);
  }
}

// ---------- fused layer (0..3): gather -> hsum RMW -> LDS -> MFMA -> gates ----------
__global__ void __launch_bounds__(256, 4) k_layer(
        const unsigned short* __restrict__ phc,
        unsigned short* __restrict__ phn,
        unsigned short* __restrict__ hsum,   // running sum (fp16); layer0: hsum = phc + agg
        const int* __restrict__ offsets, const int2* __restrict__ csr,
        const unsigned short* __restrict__ Wih_h, const unsigned short* __restrict__ Whh_h,
        const float* __restrict__ b_ih, const float* __restrict__ b_hh, int N, int first){
  __shared__ unsigned short s_a[32*DD];
  const int tid = threadIdx.x;
  const int n0 = blockIdx.x * 32;

  // ---- phase 1: paired gather — group (tid>>4) owns nodes m and m+16 concurrently ----
  {
    const int m = tid >> 4;      // 0..15
    const int q = tid & 15;      // feature octet
    const int nA = n0 + m;
    const int nB = n0 + 16 + m;
    float aA[8], aB[8];
    #pragma unroll
    for (int t = 0; t < 8; t++){ aA[t] = 0.f; aB[t] = 0.f; }
    int iA = 0, eA = 0, iB = 0, eB = 0;
    if (nA < N){ iA = offsets[nA]; eA = offsets[nA+1]; }
    if (nB < N){ iB = offsets[nB]; eB = offsets[nB+1]; }

    // joint hot loop: 4 edges of A + 4 edges of B in flight; packed-fp16 math
    while (iA + 4 <= eA && iB + 4 <= eB){
      int2 edA[4], edB[4];
      #pragma unroll
      for (int u = 0; u < 4; u++){ edA[u] = csr[iA+u]; edB[u] = csr[iB+u]; }
      u16x8 RA[4], RB[4];
      #pragma unroll
      for (int u = 0; u < 4; u++){
        RA[u] = *(const u16x8*)(phc + (size_t)edA[u].x*DD + q*8);
        RB[u] = *(const u16x8*)(phc + (size_t)edB[u].x*DD + q*8);
      }
      f16x8 sA = (f16x8){0,0,0,0,0,0,0,0};
      f16x8 sB = (f16x8){0,0,0,0,0,0,0,0};
      #pragma unroll
      for (int u = 0; u < 4; u++){
        union { int i; float f; } cA, cB; cA.i = edA[u].y; cB.i = edB[u].y;
        sA += *(const f16x8*)&RA[u] * splat8((_Float16)cA.f);
        sB += *(const f16x8*)&RB[u] * splat8((_Float16)cB.f);
      }
      #pragma unroll
      for (int t = 0; t < 8; t++){
        aA[t] += (float)sA[t];
        aB[t] += (float)sB[t];
      }
      iA += 4; iB += 4;
    }
    gather_drain(phc, csr, iA, eA, q, aA);
    gather_drain(phc, csr, iB, eB, q, aB);

    // running-sum update: hsum = (first ? phc : hsum) + agg   (fp32 add, fp16 store)
    if (nA < N){
      size_t o = (size_t)nA*DD + q*8;
      u16x8 base = first ? *(const u16x8*)(phc + o) : *(const u16x8*)(hsum + o);
      u16x8 outv;
      #pragma unroll
      for (int t = 0; t < 8; t++) outv[t] = f2h(h2f(base[t]) + aA[t]);
      *(u16x8*)(hsum + o) = outv;
    }
    if (nB < N){
      size_t o = (size_t)nB*DD + q*8;
      u16x8 base = first ? *(const u16x8*)(phc + o) : *(const u16x8*)(hsum + o);
      u16x8 outv;
      #pragma unroll
      for (int t = 0; t < 8; t++) outv[t] = f2h(h2f(base[t]) + aB[t]);
      *(u16x8*)(hsum + o) = outv;
    }

    u16x8 vA, vB;
    #pragma unroll
    for (int t = 0; t < 8; t++){ vA[t] = f2h(aA[t]); vB[t] = f2h(aB[t]); }
    const int ccA = q ^ (m & 7);
    *(u16x8*)(s_a + m*DD + ccA*8) = vA;
    *(u16x8*)(s_a + (16+m)*DD + ccA*8) = vB;   // (16+m)&7 == m&7
  }
  __syncthreads();   // the only barrier: LDS A-frags ready

  // ---- phase 2+3 per feature group (wave w -> fg w*2+g), 2 node-tiles ----
  const int w = tid >> 6, l = tid & 63, ar = l & 15, aq = l >> 4;
  int r0 = n0 + ar;      if (r0 >= N) r0 = N-1;
  int r1 = n0 + 16 + ar; if (r1 >= N) r1 = N-1;
  const size_t p0 = (size_t)r0*DD + aq*8;
  const size_t p1 = (size_t)r1*DD + aq*8;
  const int sw = ar & 7;

  for (int g = 0; g < 2; g++){
    const int fg = w*2 + g;
    f32x4 acc_i[2][3], acc_h[2][3];
    #pragma unroll
    for (int ta = 0; ta < 2; ta++)
      #pragma unroll
      for (int t = 0; t < 3; t++){
        acc_i[ta][t] = (f32x4){0.f,0.f,0.f,0.f};
        acc_h[ta][t] = (f32x4){0.f,0.f,0.f,0.f};
      }

    #pragma unroll
    for (int ks = 0; ks < 4; ks++){
      const int c = (ks*4 + aq) ^ sw;
      f16x8 ih0 = *(const f16x8*)(s_a + ar*DD       + c*8);
      f16x8 ih1 = *(const f16x8*)(s_a + (16+ar)*DD  + c*8);
      f16x8 hh0 = *(const f16x8*)(phc + p0 + ks*32);
      f16x8 hh1 = *(const f16x8*)(phc + p1 + ks*32);
      #pragma unroll
      for (int t = 0; t < 3; t++){
        size_t bo = ((size_t)((fg*3 + t)*4 + ks)*64 + l)*8;
        f16x8 bih = *(const f16x8*)(Wih_h + bo);
        f16x8 bhh = *(const f16x8*)(Whh_h + bo);
        acc_i[0][t] = __builtin_amdgcn_mfma_f32_16x16x32_f16(ih0, bih, acc_i[0][t], 0, 0, 0);
        acc_i[1][t] = __builtin_amdgcn_mfma_f32_16x16x32_f16(ih1, bih, acc_i[1][t], 0, 0, 0);
        acc_h[0][t] = __builtin_amdgcn_mfma_f32_16x16x32_f16(hh0, bhh, acc_h[0][t], 0, 0, 0);
        acc_h[1][t] = __builtin_amdgcn_mfma_f32_16x16x32_f16(hh1, bhh, acc_h[1][t], 0, 0, 0);
      }
    }

    const int f = fg*16 + ar;
    const float bir = b_ih[f], biz = b_ih[128+f], bin_ = b_ih[256+f];
    const float bhr = b_hh[f], bhz = b_hh[128+f], bhn = b_hh[256+f];
    #pragma unroll
    for (int ta = 0; ta < 2; ta++){
      #pragma unroll
      for (int r = 0; r < 4; r++){
        int n = n0 + ta*16 + aq*4 + r;
        if (n < N){
          float sir = acc_i[ta][0][r] + bir, shr = acc_h[ta][0][r] + bhr;
          float siz = acc_i[ta][1][r] + biz, shz = acc_h[ta][1][r] + bhz;
          float sin_ = acc_i[ta][2][r] + bin_, shn = acc_h[ta][2][r] + bhn;
          float rr = sigmoidf_(sir + shr);
          float zz = sigmoidf_(siz + shz);
          float nn = tanhf_(sin_ + rr*shn);
          size_t o = (size_t)n*DD + f;
          float hp = h2f(phc[o]);
          float h = (1.f - zz)*nn + zz*hp;
          phn[o] = f2h(h);
        }
      }
    }
  }
}

// ---------- decoder stage 1: hsum + 5th gather -> fp16 LDS -> MFMA matvec ----------
__global__ void __launch_bounds__(256, 8) k_dec1(const unsigned short* __restrict__ hsum,
        const unsigned short* __restrict__ ph5,
        const int* __restrict__ offsets, const int2* __restrict__ csr,
        const unsigned short* __restrict__ Wd_h, unsigned short* __restrict__ y1,
        float* __restrict__ stats_d, int N){
  __shared__ unsigned short zs[16*DD];
  __shared__ unsigned short stage[16*64];
  const int tid = threadIdx.x;
  const int n0 = blockIdx.x * 16;

  // ---- phase A: hsum + 5th gather ----
  {
    const int m = tid >> 4;      // node slot 0..15
    const int q = tid & 15;      // feature octet
    const int n = n0 + m;
    float acc[8];
    #pragma unroll
    for (int t = 0; t < 8; t++) acc[t] = 0.f;
    if (n < N){
      size_t o = (size_t)n*DD + q*8;
      u16x8 hs = *(const u16x8*)(hsum + o);
      #pragma unroll
      for (int t = 0; t < 8; t++) acc[t] = h2f(hs[t]);
      gather_drain(ph5, csr, offsets[n], offsets[n+1], q, acc);
    }
    u16x8 vh;
    #pragma unroll
    for (int t = 0; t < 8; t++) vh[t] = f2h(acc[t] * (1.f/6.f));
    const int cc = q ^ (m & 7);
    *(u16x8*)(zs + m*DD + cc*8) = vh;
  }
  __syncthreads();

  // ---- phase B: MFMA matvec z(16x128) x Wd^T(128x64), wave w -> j-tile w ----
  const int w = tid >> 6, l = tid & 63, ar = l & 15, aq = l >> 4;
  const int sw = ar & 7;
  f32x4 acc = (f32x4){0.f,0.f,0.f,0.f};
  #pragma unroll
  for (int ks = 0; ks < 4; ks++){
    const int c = (ks*4 + aq) ^ sw;
    f16x8 a = *(const f16x8*)(zs + ar*DD + c*8);
    f16x8 b = *(const f16x8*)(Wd_h + ((size_t)(w*4 + ks)*64 + l)*8);
    acc = __builtin_amdgcn_mfma_f32_16x16x32_f16(a, b, acc, 0, 0, 0);
  }
  float s = 0.f, q2 = 0.f;
  #pragma unroll
  for (int r = 0; r < 4; r++){
    int n = n0 + aq*4 + r;
    float v = acc[r];
    if (n < N){
      stage[(aq*4 + r)*64 + w*16 + ar] = f2h(v);
      s += v; q2 += v*v;
    }
  }
  s  += __shfl_xor(s, 16, 64);  s  += __shfl_xor(s, 32, 64);
  q2 += __shfl_xor(q2, 16, 64); q2 += __shfl_xor(q2, 32, 64);
  if (aq == 0){
    float* st = stats_d + (size_t)(blockIdx.x & 7)*128;
    atomicAdd(&st[w*16 + ar], s);
    atomicAdd(&st[64 + w*16 + ar], q2);
  }
  __syncthreads();
  // ---- coalesced fp16 y1 write: 256 threads x 4 u16 = 16*64 ----
  {
    int idx = tid * 4;
    int n = n0 + (idx >> 6);
    if (n < N)
      *(u16x4*)(y1 + (size_t)n0*64 + idx) = *(const u16x4*)(stage + idx);
  }
}

// ---------- decoder stage 2: sum stats copies, bn + relu + dot ----------
__global__ void __launch_bounds__(256) k_dec2(const unsigned short* __restrict__ y1,
        const float* __restrict__ gamma, const float* __restrict__ beta,
        const float* __restrict__ W_dec2, const float* __restrict__ stats_d,
        float* __restrict__ out, int N){
  const int j = threadIdx.x & 63;
  const int g = threadIdx.x >> 6;
  const int n = blockIdx.x*4 + g;
  if (n >= N) return;
  float ssum = 0.f, qsum = 0.f;
  #pragma unroll
  for (int c = 0; c < 8; c++){
    ssum += stats_d[c*128 + j];
    qsum += stats_d[c*128 + 64 + j];
  }
  float invN = 1.f / (float)N;
  float mu = ssum * invN;
  float var = qsum * invN - mu*mu;
  float v = (h2f(y1[(size_t)n*64 + j]) - mu) * rsqrtf(var + 1e-5f) * gamma[j] + beta[j];
  v = fmaxf(v, 0.f) * W_dec2[j];
  for (int off = 32; off > 0; off >>= 1) v += __shfl_down(v, off, 64);
  if (j == 0) out[n] = v;
}

extern "C" void kernel_launch(void* const* d_in, const int* in_sizes, int n_in,
                              void* d_out, int out_size, void* d_ws, size_t ws_size,
                              hipStream_t stream) {
  const int N = in_sizes[0] / 3;
  const int E = in_sizes[1] / 2;
  const int P = (N + 255) / 256;
  const int HIST_B = (E + 255) / 256;
  const int AB8 = (N*DD/8 + 255) / 256;

  const float* x     = (const float*)d_in[0];
  const int*   ei    = (const int*)d_in[1];
  const int*   src   = ei;
  const int*   dst   = ei + E;
  const float* norm  = (const float*)d_in[2];
  const float* W_enc = (const float*)d_in[3];
  const float* g_e   = (const float*)d_in[4];
  const float* b_e   = (const float*)d_in[5];
  const float* W_ih  = (const float*)d_in[6];
  const float* W_hh  = (const float*)d_in[7];
  const float* b_ih  = (const float*)d_in[8];
  const float* b_hh  = (const float*)d_in[9];
  const float* W_dec = (const float*)d_in[10];
  const float* g_d   = (const float*)d_in[11];
  const float* b_d   = (const float*)d_in[12];
  const float* W_dec2= (const float*)d_in[13];
  float* out = (float*)d_out;

  float* ws = (float*)d_ws;
  const size_t NF = (size_t)N * DD;
  float* scr    = ws;                        // NF fp32 region: h0 (fp16, pre) / y1 (fp16, decode)
  unsigned short* h0h = (unsigned short*)scr;
  unsigned short* y1h = (unsigned short*)scr; // h0 dead after k_pre2
  float* stats  = scr + NF;                  // 256 enc + 1024 dec
  float* Wt_dec = stats + 1280;              // region: 64*128 floats (Wd_h uses first 16KB)
  unsigned short* Wd_h  = (unsigned short*)Wt_dec;
  unsigned short* Wih_h = (unsigned short*)(Wt_dec + 64*128);
  unsigned short* Whh_h = Wih_h + 384*128;
  unsigned short* ph_A  = Whh_h + 384*128;   // NF ushorts each; ph_A = post-BN h
  unsigned short* ph_B  = ph_A + NF;
  unsigned short* ph_C  = ph_B + NF;
  unsigned short* hsum  = ph_C + NF;         // NF ushorts: running sum hbn + Σ agg
  int*   counts  = (int*)(hsum + NF);        // N
  int*   offsets = counts + N;               // N+1
  int*   cursors = offsets + N + 1;          // N
  int*   partials= cursors + N;              // P
  int2*  csr     = (int2*)(partials + P);    // E int2 (src, norm-bits)

  hipMemsetAsync(stats, 0, 1280*sizeof(float), stream);
  hipMemsetAsync(counts, 0, (size_t)N*sizeof(int), stream);

  k_pre1<<<PREP_B + 256 + HIST_B, 256, 0, stream>>>(
      W_ih, W_hh, W_dec, x, W_enc, dst,
      Wih_h, Whh_h, Wd_h, h0h, stats, counts, N, E);
  k_scan_part<<<P, 256, 0, stream>>>(counts, partials, N);
  k_scan_mid<<<1, 256, 0, stream>>>(partials, P, offsets, N);
  k_scan_expand<<<P, 256, 0, stream>>>(counts, partials, offsets, cursors, N);
  k_pre2<<<AB8 + HIST_B, 256, 0, stream>>>(
      h0h, g_e, b_e, stats, ph_A,
      src, dst, norm, cursors, csr, N, E, AB8);

  // layers ping-pong through B/C, leaving ph_A (post-BN h) pristine; hsum accumulates
  const int UB = (N + 31) / 32;
  k_layer<<<UB, 256, 0, stream>>>(ph_A, ph_B, hsum, offsets, csr,
                                  Wih_h, Whh_h, b_ih, b_hh, N, 1);
  k_layer<<<UB, 256, 0, stream>>>(ph_B, ph_C, hsum, offsets, csr,
                                  Wih_h, Whh_h, b_ih, b_hh, N, 0);
  k_layer<<<UB, 256, 0, stream>>>(ph_C, ph_B, hsum, offsets, csr,
                                  Wih_h, Whh_h, b_ih, b_hh, N, 0);
  k_layer<<<UB, 256, 0, stream>>>(ph_B, ph_C, hsum, offsets, csr,
                                  Wih_h, Whh_h, b_ih, b_hh, N, 0);

  k_dec1<<<(N + 15)/16, 256, 0, stream>>>(hsum, ph_C, offsets, csr,
                                          Wd_h, y1h, stats + 256, N);
  k_dec2<<<(N + 3)/4, 256, 0, stream>>>(y1h, g_d, b_d, W_dec2, stats + 256, out, N);
}